// Round 4
// baseline (508.474 us; speedup 1.0000x reference)
//
#include <hip/hip_runtime.h>

// ChildSumTreeLSTM on a static 4-ary heap tree.
// N=8192, H=256, D=300, K=4, OUT=4. Leaves = 2048..8191. Internal 0..2047 in 7 levels.
// Workspace: gx [8192][1024] f32, Hb [8192][256] f32, Cb [8192][256] f32.
//
// Structure (10 dispatches):
//   1. gx_gemm   — XCD-swizzled (col-tiles of a row-tile share an XCD -> emb
//                  L2-resident; FETCH 41MB->~13MB), dead leaf-f tiles skipped.
//   2. leaf_kernel (4 nodes/block)
//   3-9. level_fused2 x7 — block = (4-node group, 64-row block): computes all
//        7 GEMV sections for its 64 rows (4 gates x 64 rows = 256KB W, LDS-
//        staged in 32-k chunks, coalesced), quad-reduce, pointwise in-block.
//        Pointwise is elementwise in t, so row-split has NO cross-block dep.
//        Root dispatch loops all 4 row-blocks in one block and emits out.
// Lessons encoded: no grid barriers (round 1: ~170us/sync); per-block W
// footprint 256KB not 1MB (rounds 2-3: serial W streaming ate the tails).

#define N_NODES 8192
#define HDIM 256
#define DDIM 300
#define GXC 1024
#define LEAF_FIRST 2048
#define WH_STRIDE 65536   // 256*256
#define NG 4              // nodes per fused block
#define KC 32             // k-chunk
#define WP 66             // Ws row-dim pad (bank-conflict-free: 2-way max)

__device__ __forceinline__ float sigf(float x) { return 1.0f / (1.0f + __expf(-x)); }

// ---------- Kernel 1: gx[n][c] = emb[xs[n]] · Wx[c] + bx[c]  (64x64 tile) ----
__global__ __launch_bounds__(256) void gx_gemm(
    const int* __restrict__ xs, const float* __restrict__ emb,
    const float* __restrict__ Wx, const float* __restrict__ bx,
    float* __restrict__ gx)
{
    // XCD-aware remap: dispatch is x-fastest linear, XCD = lid % 8 (round-robin).
    // Map so all 16 col-tiles of a row-tile land on ONE XCD -> emb rows fetched
    // from HBM once, then L2-hit for the other 15 tiles.
    const int lid  = blockIdx.x + blockIdx.y * gridDim.x;   // 0..2047
    const int rowt = (lid & 7) + ((lid >> 3) & 15) * 8;     // 0..127
    const int colt = lid >> 7;                              // 0..15
    const int n0 = rowt * 64;
    const int c0 = colt * 64;
    // Leaf rows' f-gate columns (256..511) are never read downstream: skip.
    if (n0 >= LEAF_FIRST && c0 >= 256 && c0 < 512) return;

    __shared__ __align__(16) float As[16][68];
    __shared__ __align__(16) float Bs[16][68];
    const int tid  = threadIdx.x;
    const int sr   = tid >> 2;
    const int sk   = (tid & 3) << 2;
    const int trow = (tid >> 4) << 2;
    const int tcol = (tid & 15) << 2;

    const long arow = (long)xs[n0 + sr] * DDIM;
    const long brow = (long)(c0 + sr) * DDIM;

    float acc[4][4] = {};

    for (int k0 = 0; k0 < DDIM; k0 += 16) {
        float4 av, bv;
        if (k0 + sk < DDIM) {
            av = *(const float4*)(emb + arow + k0 + sk);
            bv = *(const float4*)(Wx  + brow + k0 + sk);
        } else {
            av = make_float4(0.f, 0.f, 0.f, 0.f);
            bv = make_float4(0.f, 0.f, 0.f, 0.f);
        }
        __syncthreads();
        As[sk+0][sr] = av.x; As[sk+1][sr] = av.y; As[sk+2][sr] = av.z; As[sk+3][sr] = av.w;
        Bs[sk+0][sr] = bv.x; Bs[sk+1][sr] = bv.y; Bs[sk+2][sr] = bv.z; Bs[sk+3][sr] = bv.w;
        __syncthreads();
        #pragma unroll
        for (int k = 0; k < 16; k++) {
            float4 a = *(const float4*)&As[k][trow];
            float4 b = *(const float4*)&Bs[k][tcol];
            float avv[4] = {a.x, a.y, a.z, a.w};
            float bvv[4] = {b.x, b.y, b.z, b.w};
            #pragma unroll
            for (int i = 0; i < 4; i++)
                #pragma unroll
                for (int j = 0; j < 4; j++)
                    acc[i][j] = fmaf(avv[i], bvv[j], acc[i][j]);
        }
    }

    #pragma unroll
    for (int i = 0; i < 4; i++) {
        const int col = c0 + tcol;
        float4 r;
        r.x = acc[i][0] + bx[col + 0];
        r.y = acc[i][1] + bx[col + 1];
        r.z = acc[i][2] + bx[col + 2];
        r.w = acc[i][3] + bx[col + 3];
        *(float4*)(gx + (long)(n0 + trow + i) * GXC + col) = r;
    }
}

// ---------- Kernel 2: leaves — pure elementwise (4 nodes/block) -------------
__global__ __launch_bounds__(256) void leaf_kernel(
    const float* __restrict__ gx, const float* __restrict__ bh,
    float* __restrict__ Hb, float* __restrict__ Cb)
{
    const int t = threadIdx.x;
    const float bi = bh[t], bo = bh[512 + t], bu = bh[768 + t];
    #pragma unroll
    for (int s = 0; s < 4; s++) {
        const int node = LEAF_FIRST + blockIdx.x * 4 + s;
        const float* g = gx + (long)node * GXC;
        const float gi = g[t]       + bi;
        const float go = g[512 + t] + bo;
        const float gu = g[768 + t] + bu;
        const float c  = sigf(gi) * tanhf(gu);
        const float h  = sigf(go) * tanhf(c);
        Hb[(long)node * HDIM + t] = h;
        Cb[(long)node * HDIM + t] = c;
    }
}

// ---------- Kernel 3: fused level kernel, row-split -------------------------
// Grid: (ceil(M/NG), 4)  [root: (1,1), loops rb internally, emits out].
// Block: 256 thr. Per block: NG nodes, 64 output rows (rb*64..+63).
//  - stage NG nodes' children h (masked) + hs in LDS (once)
//  - k-chunk loop: stage 4 gates x 64 rows x 32 k of Wh (coalesced, k-major
//    LDS layout [gate][k][row+pad] -> stride-1 conflict-free compute reads)
//  - acc[g][7] per thread (q=row, j=k-lane); quad-reduce -> Ds
//  - pointwise for the 64 rows in-block (elementwise in t) -> Hb, Cb
__global__ __launch_bounds__(256) void level_fused2(
    int first, int M, int do_out,
    const float* __restrict__ gx, const int* __restrict__ child_idx,
    const float* __restrict__ child_mask, const float* __restrict__ Wh,
    const float* __restrict__ bh, float* __restrict__ Hb, float* __restrict__ Cb,
    const float* __restrict__ Wout, const float* __restrict__ bout,
    float* __restrict__ out)
{
    __shared__ __align__(16) float Xh[NG][HDIM];       // child-h sum      4KB
    __shared__ __align__(16) float Xc[NG][4][HDIM];    // children h      16KB
    __shared__ __align__(16) float Ws[4][KC][WP];      // W chunk       33.8KB
    __shared__ float Ds[NG][7][64];                    // GEMV results     7KB
    __shared__ float hroot[HDIM];
    __shared__ float logits[4];

    const int t   = threadIdx.x;
    const int ng0 = blockIdx.x * NG;

    // ---- stage children h (masked) into LDS, once --------------------------
    {
        const int sg   = t >> 6;          // node in group
        const int sch  = (t >> 4) & 3;    // child
        const int sk16 = (t & 15) << 4;   // 16-float slice
        const int nl = ng0 + sg;
        float m = 0.f; long crow = 0;
        if (nl < M) {
            const int n = first + nl;
            crow = (long)child_idx[n * 4 + sch] * HDIM;
            m    = child_mask[n * 4 + sch];
        }
        float4 v[4];
        #pragma unroll
        for (int i = 0; i < 4; i++) v[i] = make_float4(0.f, 0.f, 0.f, 0.f);
        if (m != 0.f) {
            #pragma unroll
            for (int i = 0; i < 4; i++)
                v[i] = *(const float4*)(Hb + crow + sk16 + i * 4);
        }
        #pragma unroll
        for (int i = 0; i < 4; i++)
            *(float4*)&Xc[sg][sch][sk16 + i * 4] = v[i];
    }
    __syncthreads();
    for (int idx = t; idx < NG * HDIM; idx += 256) {
        const int g = idx >> 8, k = idx & 255;
        Xh[g][k] = Xc[g][0][k] + Xc[g][1][k] + Xc[g][2][k] + Xc[g][3][k];
    }
    // (covered by the first chunk's __syncthreads below)

    const float* Wg[4] = { Wh,                  // i
                           Wh + 2 * WH_STRIDE,  // o
                           Wh + 3 * WH_STRIDE,  // u
                           Wh + 1 * WH_STRIDE };// f
    const int q   = t >> 2;          // output row within rb
    const int j   = t & 3;           // k-lane within quad
    const int gi4 = t >> 6;          // staging: gate (one per wave)
    const int r8  = (t & 63) >> 3;   // staging: row low bits
    const int ks  = t & 7;           // staging: k-slot

    const int rb0 = do_out ? 0 : blockIdx.y;
    const int rb1 = do_out ? 4 : (int)blockIdx.y + 1;

    for (int rb = rb0; rb < rb1; rb++) {
        float acc[NG][7];
        #pragma unroll
        for (int g = 0; g < NG; g++)
            #pragma unroll
            for (int s = 0; s < 7; s++) acc[g][s] = 0.f;

        for (int kc = 0; kc < HDIM / KC; kc++) {
            __syncthreads();   // Ws safe to overwrite
            // stage W chunk: wave gi4 loads gate gi4, rows rb*64.., k kc*32..
            {
                const float* wb = Wg[gi4] + (long)(rb * 64) * HDIM + kc * KC + ks * 4;
                #pragma unroll
                for (int rr = 0; rr < 8; rr++) {
                    const int row = rr * 8 + r8;
                    const float4 wv = *(const float4*)(wb + (long)row * HDIM);
                    Ws[gi4][ks * 4 + 0][row] = wv.x;
                    Ws[gi4][ks * 4 + 1][row] = wv.y;
                    Ws[gi4][ks * 4 + 2][row] = wv.z;
                    Ws[gi4][ks * 4 + 3][row] = wv.w;
                }
            }
            __syncthreads();
            // compute: thread (q, j); j covers k = j*8 .. j*8+7 of the chunk
            #pragma unroll
            for (int kk4 = 0; kk4 < 2; kk4++) {
                const int kb = j * 8 + kk4 * 4;
                const int kg = kc * KC + kb;
                float w0[4], w1[4], w2[4], w3[4];
                #pragma unroll
                for (int i = 0; i < 4; i++) {
                    w0[i] = Ws[0][kb + i][q];
                    w1[i] = Ws[1][kb + i][q];
                    w2[i] = Ws[2][kb + i][q];
                    w3[i] = Ws[3][kb + i][q];
                }
                #pragma unroll
                for (int g = 0; g < NG; g++) {
                    const float4 hs = *(const float4*)&Xh[g][kg];
                    const float hv[4] = {hs.x, hs.y, hs.z, hs.w};
                    #pragma unroll
                    for (int i = 0; i < 4; i++) {
                        acc[g][0] = fmaf(w0[i], hv[i], acc[g][0]);
                        acc[g][1] = fmaf(w1[i], hv[i], acc[g][1]);
                        acc[g][2] = fmaf(w2[i], hv[i], acc[g][2]);
                    }
                    #pragma unroll
                    for (int ch = 0; ch < 4; ch++) {
                        const float4 cv = *(const float4*)&Xc[g][ch][kg];
                        const float cvv[4] = {cv.x, cv.y, cv.z, cv.w};
                        #pragma unroll
                        for (int i = 0; i < 4; i++)
                            acc[g][3 + ch] = fmaf(w3[i], cvv[i], acc[g][3 + ch]);
                    }
                }
            }
        }

        // quad-reduce (over j) -> Ds
        #pragma unroll
        for (int g = 0; g < NG; g++)
            #pragma unroll
            for (int s = 0; s < 7; s++) {
                float v = acc[g][s];
                v += __shfl_xor(v, 1, 64);
                v += __shfl_xor(v, 2, 64);
                if (j == 0) Ds[g][s][q] = v;
            }
        __syncthreads();

        // pointwise for rows rb*64..+63 of the NG nodes
        {
            const int pg = t >> 6, r = t & 63;
            const int nl = ng0 + pg;
            if (nl < M) {
                const int n    = first + nl;
                const int grow = rb * 64 + r;
                const float* gg = gx + (long)n * GXC;
                const float gi  = gg[grow]       + bh[grow]       + Ds[pg][0][r];
                const float gfb = gg[256 + grow] + bh[256 + grow];
                const float go  = gg[512 + grow] + bh[512 + grow] + Ds[pg][1][r];
                const float gu  = gg[768 + grow] + bh[768 + grow] + Ds[pg][2][r];
                float c = sigf(gi) * tanhf(gu);
                #pragma unroll
                for (int ch = 0; ch < 4; ch++) {
                    const float m = child_mask[n * 4 + ch];
                    if (m != 0.f) {
                        const long crow = (long)child_idx[n * 4 + ch] * HDIM;
                        c = fmaf(sigf(gfb + Ds[pg][3 + ch][r]), Cb[crow + grow], c);
                    }
                }
                const float h = sigf(go) * tanhf(c);
                Hb[(long)n * HDIM + grow] = h;
                Cb[(long)n * HDIM + grow] = c;
                if (do_out && n == 0) hroot[grow] = h;
            }
        }
        // next rb's first chunk-sync protects Ws/Ds reuse
    }

    // ---- root logits + log_softmax (root dispatch only) --------------------
    if (do_out) {
        __syncthreads();
        const int o    = t >> 6;
        const int lane = t & 63;
        float s = 0.f;
        for (int jj = lane; jj < HDIM; jj += 64)
            s = fmaf(Wout[o * HDIM + jj], hroot[jj], s);
        #pragma unroll
        for (int off = 32; off > 0; off >>= 1)
            s += __shfl_down(s, off, 64);
        if (lane == 0) logits[o] = s + bout[o];
        __syncthreads();
        if (t == 0) {
            float m = logits[0];
            #pragma unroll
            for (int i = 1; i < 4; i++) m = fmaxf(m, logits[i]);
            float se = 0.f;
            #pragma unroll
            for (int i = 0; i < 4; i++) se += __expf(logits[i] - m);
            const float lse = m + __logf(se);
            #pragma unroll
            for (int i = 0; i < 4; i++) out[i] = logits[i] - lse;
        }
    }
}

extern "C" void kernel_launch(void* const* d_in, const int* in_sizes, int n_in,
                              void* d_out, int out_size, void* d_ws, size_t ws_size,
                              hipStream_t stream)
{
    const int*   xs         = (const int*)  d_in[0];
    const int*   child_idx  = (const int*)  d_in[1];
    const float* child_mask = (const float*)d_in[2];
    const float* emb        = (const float*)d_in[3];
    const float* Wx         = (const float*)d_in[4];
    const float* bx         = (const float*)d_in[5];
    const float* Wh         = (const float*)d_in[6];
    const float* bh         = (const float*)d_in[7];
    const float* Wout       = (const float*)d_in[8];
    const float* bout       = (const float*)d_in[9];
    float* out = (float*)d_out;

    float* gxb = (float*)d_ws;
    float* Hb  = gxb + (size_t)N_NODES * GXC;
    float* Cb  = Hb  + (size_t)N_NODES * HDIM;

    gx_gemm<<<dim3(GXC / 64, N_NODES / 64), 256, 0, stream>>>(xs, emb, Wx, bx, gxb);
    leaf_kernel<<<(N_NODES - LEAF_FIRST) / 4, 256, 0, stream>>>(gxb, bh, Hb, Cb);

    const int pf[7] = {1365, 341, 85, 21, 5, 1, 0};
    const int pc[7] = { 683, 1024, 256, 64, 16, 4, 1};
    for (int p = 0; p < 7; p++) {
        const int M = pc[p];
        const int do_out = (p == 6) ? 1 : 0;
        dim3 grid = do_out ? dim3(1, 1) : dim3((M + NG - 1) / NG, 4);
        level_fused2<<<grid, 256, 0, stream>>>(pf[p], M, do_out,
                                               gxb, child_idx, child_mask, Wh, bh,
                                               Hb, Cb, Wout, bout, out);
    }
}

// Round 5
// 322.674 us; speedup vs baseline: 1.5758x; 1.5758x over previous
//
#include <hip/hip_runtime.h>

// ChildSumTreeLSTM on a static 4-ary heap tree.
// N=8192, H=256, D=300, K=4, OUT=4. Leaves = 2048..8191. Internal 0..2047 in 7 levels.
// Workspace: gx [8192][1024] f32, Hb [8192][256] f32, Cb [8192][256] f32.
// D (level-GEMM scratch, <=7.3 MB) aliases gx rows 2048.. (dead after leaf_kernel).
//
// Structure = round-0 champion (385us) + software pipelining:
//   1. gx_gemm      — pipelined (prefetch chunk k+1 into regs during compute k);
//                     XCD swizzle (emb L2-resident); dead leaf-f tiles skipped.
//   2. leaf_kernel  — 4 nodes/block.
//   3-16. 7 levels: level_gemm (pipelined) + level_pointwise;
//         out folded into the last (M=1) pointwise.
// Hard-won structural rules (rounds 1-4): NO grid barriers (~170us each on
// non-coherent XCD L2s); NO fused GEMV levels (per-block serial W streaming);
// tail levels use the simplest kernels (tiny grids expose any latency chain:
// round-4's chunked tails ran 133us at 0.05% VALU).

#define N_NODES 8192
#define HDIM 256
#define DDIM 300
#define GXC 1024
#define LEAF_FIRST 2048
#define WH_STRIDE 65536   // 256*256

__device__ __forceinline__ float sigf(float x) { return 1.0f / (1.0f + __expf(-x)); }

// ---------- Kernel 1: gx[n][c] = emb[xs[n]] · Wx[c] + bx[c]  (64x64 tile) ----
__global__ __launch_bounds__(256) void gx_gemm(
    const int* __restrict__ xs, const float* __restrict__ emb,
    const float* __restrict__ Wx, const float* __restrict__ bx,
    float* __restrict__ gx)
{
    // XCD-aware remap: all 16 col-tiles of a row-tile -> same XCD (lid%8),
    // so the row's 64 emb rows are fetched from HBM once, L2-hit after.
    const int lid  = blockIdx.x + blockIdx.y * gridDim.x;   // 0..2047
    const int rowt = (lid & 7) + ((lid >> 3) & 15) * 8;     // 0..127
    const int colt = lid >> 7;                              // 0..15
    const int n0 = rowt * 64;
    const int c0 = colt * 64;
    // Leaf rows' f-gate columns (256..511) are never read downstream: skip.
    if (n0 >= LEAF_FIRST && c0 >= 256 && c0 < 512) return;

    __shared__ __align__(16) float As[16][68];
    __shared__ __align__(16) float Bs[16][68];
    const int tid  = threadIdx.x;
    const int sr   = tid >> 2;
    const int sk   = (tid & 3) << 2;
    const int trow = (tid >> 4) << 2;
    const int tcol = (tid & 15) << 2;

    const long arow = (long)xs[n0 + sr] * DDIM;
    const long brow = (long)(c0 + sr) * DDIM;

    float acc[4][4] = {};

    // prefetch chunk 0
    float4 av = make_float4(0.f, 0.f, 0.f, 0.f);
    float4 bv = make_float4(0.f, 0.f, 0.f, 0.f);
    if (sk < DDIM) {                       // always true, kept for symmetry
        av = *(const float4*)(emb + arow + sk);
        bv = *(const float4*)(Wx  + brow + sk);
    }

    for (int k0 = 0; k0 < DDIM; k0 += 16) {
        __syncthreads();
        As[sk+0][sr] = av.x; As[sk+1][sr] = av.y; As[sk+2][sr] = av.z; As[sk+3][sr] = av.w;
        Bs[sk+0][sr] = bv.x; Bs[sk+1][sr] = bv.y; Bs[sk+2][sr] = bv.z; Bs[sk+3][sr] = bv.w;
        __syncthreads();

        // prefetch chunk k0+16 (overlaps with compute below)
        const int kn = k0 + 16;
        av = make_float4(0.f, 0.f, 0.f, 0.f);
        bv = make_float4(0.f, 0.f, 0.f, 0.f);
        if (kn + sk < DDIM) {
            av = *(const float4*)(emb + arow + kn + sk);
            bv = *(const float4*)(Wx  + brow + kn + sk);
        }

        #pragma unroll
        for (int k = 0; k < 16; k++) {
            float4 a = *(const float4*)&As[k][trow];
            float4 b = *(const float4*)&Bs[k][tcol];
            float avv[4] = {a.x, a.y, a.z, a.w};
            float bvv[4] = {b.x, b.y, b.z, b.w};
            #pragma unroll
            for (int i = 0; i < 4; i++)
                #pragma unroll
                for (int j = 0; j < 4; j++)
                    acc[i][j] = fmaf(avv[i], bvv[j], acc[i][j]);
        }
    }

    #pragma unroll
    for (int i = 0; i < 4; i++) {
        const int col = c0 + tcol;
        float4 r;
        r.x = acc[i][0] + bx[col + 0];
        r.y = acc[i][1] + bx[col + 1];
        r.z = acc[i][2] + bx[col + 2];
        r.w = acc[i][3] + bx[col + 3];
        *(float4*)(gx + (long)(n0 + trow + i) * GXC + col) = r;
    }
}

// ---------- Kernel 2: leaves — pure elementwise (4 nodes/block) -------------
__global__ __launch_bounds__(256) void leaf_kernel(
    const float* __restrict__ gx, const float* __restrict__ bh,
    float* __restrict__ Hb, float* __restrict__ Cb)
{
    const int t = threadIdx.x;
    const float bi = bh[t], bo = bh[512 + t], bu = bh[768 + t];
    #pragma unroll
    for (int s = 0; s < 4; s++) {
        const int node = LEAF_FIRST + blockIdx.x * 4 + s;
        const float* g = gx + (long)node * GXC;
        const float gi = g[t]       + bi;
        const float go = g[512 + t] + bo;
        const float gu = g[768 + t] + bu;
        const float c  = sigf(gi) * tanhf(gu);
        const float h  = sigf(go) * tanhf(c);
        Hb[(long)node * HDIM + t] = h;
        Cb[(long)node * HDIM + t] = c;
    }
}

// ---------- Kernel 3: per-level GEMM  D[sec][nl][r] = Wh_g[r,:]·X[nl,:] ------
// blockIdx.y = sec: 0=i (X=hs), 1=o (X=hs), 2=u (X=hs), 3..6=f child c (X=h_c)
// blockIdx.x = 64-col tile over nodes; blockIdx.z = 64-row tile (4 of them).
// Pipelined: chunk k+1's global loads (children h, W row) issued into regs
// during chunk k's compute; masked-child sum deferred to the LDS-write phase.
__global__ __launch_bounds__(256) void level_gemm(
    int first, int M, const float* __restrict__ Hb,
    const int* __restrict__ child_idx, const float* __restrict__ child_mask,
    const float* __restrict__ Wh, float* __restrict__ D)
{
    __shared__ __align__(16) float Xs[16][68];
    __shared__ __align__(16) float Ws[16][68];
    const int tid  = threadIdx.x;
    const int sec  = blockIdx.y;
    const int c0   = blockIdx.x * 64;
    const int r0   = blockIdx.z * 64;
    const int sr   = tid >> 2;
    const int sk   = (tid & 3) << 2;
    const int trow = (tid >> 4) << 2;
    const int tcol = (tid & 15) << 2;

    const float* Wg;
    if      (sec == 0) Wg = Wh;                  // i
    else if (sec == 1) Wg = Wh + 2 * WH_STRIDE;  // o
    else if (sec == 2) Wg = Wh + 3 * WH_STRIDE;  // u
    else               Wg = Wh + 1 * WH_STRIDE;  // f

    const int  nl    = c0 + sr;
    const bool valid = nl < M;
    int   ci[4];
    float cm[4] = {0.f, 0.f, 0.f, 0.f};
    if (valid) {
        const int n = first + nl;
        if (sec < 3) {
            #pragma unroll
            for (int k = 0; k < 4; k++) {
                ci[k] = child_idx[n * 4 + k];
                cm[k] = child_mask[n * 4 + k];
            }
        } else {
            ci[0] = child_idx[n * 4 + (sec - 3)];
            cm[0] = child_mask[n * 4 + (sec - 3)];
        }
    }
    const long wrow = (long)(r0 + sr) * HDIM;

    float acc[4][4] = {};

    // raw prefetch registers for the staged chunk
    float4 hvr[4], wvr;

    // prefetch chunk 0
    {
        #pragma unroll
        for (int k = 0; k < 4; k++) hvr[k] = make_float4(0.f, 0.f, 0.f, 0.f);
        if (valid) {
            if (sec < 3) {
                #pragma unroll
                for (int k = 0; k < 4; k++)
                    if (cm[k] != 0.f)
                        hvr[k] = *(const float4*)(Hb + ci[k] * HDIM + sk);
            } else if (cm[0] != 0.f) {
                hvr[0] = *(const float4*)(Hb + ci[0] * HDIM + sk);
            }
        }
        wvr = *(const float4*)(Wg + wrow + sk);
    }

    for (int k0 = 0; k0 < HDIM; k0 += 16) {
        __syncthreads();
        // masked children were never loaded -> hvr[k] stays zero; sum is safe
        float4 xv;
        xv.x = hvr[0].x + hvr[1].x + hvr[2].x + hvr[3].x;
        xv.y = hvr[0].y + hvr[1].y + hvr[2].y + hvr[3].y;
        xv.z = hvr[0].z + hvr[1].z + hvr[2].z + hvr[3].z;
        xv.w = hvr[0].w + hvr[1].w + hvr[2].w + hvr[3].w;
        Xs[sk+0][sr] = xv.x; Xs[sk+1][sr] = xv.y; Xs[sk+2][sr] = xv.z; Xs[sk+3][sr] = xv.w;
        Ws[sk+0][sr] = wvr.x; Ws[sk+1][sr] = wvr.y; Ws[sk+2][sr] = wvr.z; Ws[sk+3][sr] = wvr.w;
        __syncthreads();

        // prefetch chunk k0+16 (overlaps with compute below)
        const int kn = k0 + 16;
        if (kn < HDIM) {
            #pragma unroll
            for (int k = 0; k < 4; k++) hvr[k] = make_float4(0.f, 0.f, 0.f, 0.f);
            if (valid) {
                if (sec < 3) {
                    #pragma unroll
                    for (int k = 0; k < 4; k++)
                        if (cm[k] != 0.f)
                            hvr[k] = *(const float4*)(Hb + ci[k] * HDIM + kn + sk);
                } else if (cm[0] != 0.f) {
                    hvr[0] = *(const float4*)(Hb + ci[0] * HDIM + kn + sk);
                }
            }
            wvr = *(const float4*)(Wg + wrow + kn + sk);
        }

        #pragma unroll
        for (int k = 0; k < 16; k++) {
            float4 a = *(const float4*)&Ws[k][trow];
            float4 b = *(const float4*)&Xs[k][tcol];
            float avv[4] = {a.x, a.y, a.z, a.w};
            float bvv[4] = {b.x, b.y, b.z, b.w};
            #pragma unroll
            for (int i = 0; i < 4; i++)
                #pragma unroll
                for (int j = 0; j < 4; j++)
                    acc[i][j] = fmaf(avv[i], bvv[j], acc[i][j]);
        }
    }

    #pragma unroll
    for (int j = 0; j < 4; j++) {
        const int col = c0 + tcol + j;
        if (col < M) {
            float4 r;
            r.x = acc[0][j]; r.y = acc[1][j]; r.z = acc[2][j]; r.w = acc[3][j];
            *(float4*)(D + ((long)(sec * M + col)) * HDIM + r0 + trow) = r;
        }
    }
}

// ---------- Kernel 4: per-level pointwise — combine D + gx -> h, c ----------
// do_out: on the M=1 (root) dispatch, also emit logits + log_softmax.
__global__ __launch_bounds__(256) void level_pointwise(
    int first, int M, int do_out,
    const float* __restrict__ gx, const float* __restrict__ D,
    const int* __restrict__ child_idx, const float* __restrict__ child_mask,
    const float* __restrict__ bh, float* __restrict__ Hb, float* __restrict__ Cb,
    const float* __restrict__ Wout, const float* __restrict__ bout,
    float* __restrict__ out)
{
    __shared__ float hroot[HDIM];
    __shared__ float logits[4];
    const int nl = blockIdx.x;
    const int n  = first + nl;
    const int t  = threadIdx.x;
    const float di  = D[((long)(0 * M + nl)) * HDIM + t];
    const float dO  = D[((long)(1 * M + nl)) * HDIM + t];
    const float du  = D[((long)(2 * M + nl)) * HDIM + t];
    const float* g = gx + (long)n * GXC;
    const float gi  = g[t]       + bh[t]       + di;
    const float gfb = g[256 + t] + bh[256 + t];
    const float go  = g[512 + t] + bh[512 + t] + dO;
    const float gu  = g[768 + t] + bh[768 + t] + du;

    float c = sigf(gi) * tanhf(gu);
    #pragma unroll
    for (int k = 0; k < 4; k++) {
        const float m = child_mask[n * 4 + k];
        if (m != 0.f) {
            const float df = D[((long)((3 + k) * M + nl)) * HDIM + t];
            const float cc = Cb[(long)child_idx[n * 4 + k] * HDIM + t];
            c = fmaf(sigf(gfb + df), cc, c);
        }
    }
    const float h = sigf(go) * tanhf(c);
    Hb[(long)n * HDIM + t] = h;
    Cb[(long)n * HDIM + t] = c;

    if (do_out) {
        hroot[t] = h;                       // n==0, single block
        __syncthreads();
        const int o    = t >> 6;
        const int lane = t & 63;
        float s = 0.f;
        for (int jj = lane; jj < HDIM; jj += 64)
            s = fmaf(Wout[o * HDIM + jj], hroot[jj], s);
        #pragma unroll
        for (int off = 32; off > 0; off >>= 1)
            s += __shfl_down(s, off, 64);
        if (lane == 0) logits[o] = s + bout[o];
        __syncthreads();
        if (t == 0) {
            float m = logits[0];
            #pragma unroll
            for (int i = 1; i < 4; i++) m = fmaxf(m, logits[i]);
            float se = 0.f;
            #pragma unroll
            for (int i = 0; i < 4; i++) se += __expf(logits[i] - m);
            const float lse = m + __logf(se);
            #pragma unroll
            for (int i = 0; i < 4; i++) out[i] = logits[i] - lse;
        }
    }
}

extern "C" void kernel_launch(void* const* d_in, const int* in_sizes, int n_in,
                              void* d_out, int out_size, void* d_ws, size_t ws_size,
                              hipStream_t stream)
{
    const int*   xs         = (const int*)  d_in[0];
    const int*   child_idx  = (const int*)  d_in[1];
    const float* child_mask = (const float*)d_in[2];
    const float* emb        = (const float*)d_in[3];
    const float* Wx         = (const float*)d_in[4];
    const float* bx         = (const float*)d_in[5];
    const float* Wh         = (const float*)d_in[6];
    const float* bh         = (const float*)d_in[7];
    const float* Wout       = (const float*)d_in[8];
    const float* bout       = (const float*)d_in[9];
    float* out = (float*)d_out;

    float* gxb = (float*)d_ws;
    float* Hb  = gxb + (size_t)N_NODES * GXC;
    float* Cb  = Hb  + (size_t)N_NODES * HDIM;
    // D aliases the gx rows of leaf nodes (dead after leaf_kernel).
    // Max size: 7*1024*256 floats = 7.3 MB -> gx rows 2048..~3840.
    float* Dbuf = gxb + (size_t)LEAF_FIRST * GXC;

    gx_gemm<<<dim3(GXC / 64, N_NODES / 64), 256, 0, stream>>>(xs, emb, Wx, bx, gxb);
    leaf_kernel<<<(N_NODES - LEAF_FIRST) / 4, 256, 0, stream>>>(gxb, bh, Hb, Cb);

    const int pf[7] = {1365, 341, 85, 21, 5, 1, 0};
    const int pc[7] = { 683, 1024, 256, 64, 16, 4, 1};
    for (int p = 0; p < 7; p++) {
        const int M = pc[p];
        dim3 grid((M + 63) / 64, 7, 4);
        level_gemm<<<grid, 256, 0, stream>>>(pf[p], M, Hb, child_idx, child_mask,
                                             Wh, Dbuf);
        level_pointwise<<<M, 256, 0, stream>>>(pf[p], M, (p == 6) ? 1 : 0,
                                               gxb, Dbuf, child_idx, child_mask,
                                               bh, Hb, Cb, Wout, bout, out);
    }
}